// Round 3
// baseline (8924.680 us; speedup 1.0000x reference)
//
#include <hip/hip_runtime.h>
#include <cstdint>
#include <cstddef>

#define MM 4096
#define NSTEP 50
#define DD 100
#define HID 512
#define K0P 128
#define SIGC 0.4f
#define RC 0.05f
#define BMR 32
#define NWG (MM / BMR)   // 128

typedef __bf16 bf16x8 __attribute__((ext_vector_type(8)));
typedef float  f32x4  __attribute__((ext_vector_type(4)));

union Pack4 { __bf16 h[4]; uint2 u2; };

// ---------- weight prep ----------
__global__ void k_transpose(const float* __restrict__ in, __bf16* __restrict__ out,
                            int Ksrc, int Kpad, int N) {
    int idx = blockIdx.x * 256 + threadIdx.x;
    if (idx >= N * Kpad) return;
    int n = idx / Kpad, k = idx - n * Kpad;
    out[idx] = (k < Ksrc) ? (__bf16)in[k * N + n] : (__bf16)0.f;
}

__global__ void k_cast(const float* __restrict__ in, __bf16* __restrict__ out,
                       int Rsrc, int Rpad, int C) {
    int idx = blockIdx.x * 256 + threadIdx.x;
    if (idx >= Rpad * C) return;
    int r = idx / C;
    out[idx] = (r < Rsrc) ? (__bf16)in[idx] : (__bf16)0.f;
}

// ---------- tX writer (swizzled bf16 [32][128], row stride 256B) ----------
__device__ __forceinline__ void write_tX(char* S, int m, int dg, int d0,
                                         const float* x, float tval) {
    #pragma unroll
    for (int i = 0; i < 13; i++) {
        int d = d0 + i;
        int col = 1 + d;
        float v = (d < DD) ? x[i] : 0.f;
        int po = m * 256 + (((col >> 3) ^ (m & 7)) << 4) + (col & 7) * 2;
        *(__bf16*)(S + po) = (__bf16)v;
    }
    if (dg == 0) {
        int po = m * 256 + ((m & 7) << 4);
        *(__bf16*)(S + po) = (__bf16)tval;
    }
    if (dg == 7) {
        #pragma unroll
        for (int c = 105; c < 128; c++) {
            int po = m * 256 + (((c >> 3) ^ (m & 7)) << 4) + (c & 7) * 2;
            *(__bf16*)(S + po) = (__bf16)0.f;
        }
    }
}

// ---------- one GEMM phase: C[m][n] = sum_k A[m][k] * B[n][k] ----------
// A: LDS (swizzled), B: global (L2-resident weights), 4 waves, wave tile 32 x (NJ*16).
// EPI 0: fwd:      v+=bias; sin->sOut, cos->sStash (packed bf16)
// EPI 1: fwd-last: v+=bias; cos*W4->sOut(g3); u partial -> u_lds (LDS atomics)
// EPI 2: bwd:      v*=sStash; ->sOut
// EPI 3: bwd-last: v (f32) -> sOut (Z, [32][128] f32, no swizzle)
template <int NK, int NJ, int EPI>
__device__ __forceinline__ void phase(
    int tid, const char* __restrict__ sA, int aRS,
    const __bf16* __restrict__ Bw, int K,
    const float* __restrict__ bias, const float* __restrict__ W4,
    char* __restrict__ sOut, const char* __restrict__ sStash,
    float* __restrict__ u_lds) {

    const int lane = tid & 63;
    const int wave = tid >> 6;
    const int lr = lane & 15, lg = lane >> 4;
    const int wc = wave * (NJ * 16);
    const int m0 = lr, m1 = 16 + lr;

    f32x4 acc[2][NJ] = {};
    bf16x8 aA[2], aB[2], bA[NJ], bB[NJ];

    const __bf16* bp = Bw + (size_t)(wc + lr) * K + lg * 8;

    #define LOADA(dst, ks)                                                        \
        {   int ch = (ks) * 4 + lg;                                               \
            dst[0] = *(const bf16x8*)(sA + m0 * aRS + ((ch ^ (m0 & 7)) << 4));    \
            dst[1] = *(const bf16x8*)(sA + m1 * aRS + ((ch ^ (m1 & 7)) << 4)); }
    #define LOADB(dst, ks)                                                        \
        {   _Pragma("unroll")                                                     \
            for (int nj = 0; nj < NJ; nj++)                                       \
                dst[nj] = *(const bf16x8*)(bp + nj * 16 * K + (ks) * 32); }
    #define DOMFMA(av, bv)                                                        \
        {   _Pragma("unroll")                                                     \
            for (int mi = 0; mi < 2; mi++)                                        \
                _Pragma("unroll")                                                 \
                for (int nj = 0; nj < NJ; nj++)                                   \
                    acc[mi][nj] = __builtin_amdgcn_mfma_f32_16x16x32_bf16(        \
                        bv[nj], av[mi], acc[mi][nj], 0, 0, 0); }

    LOADA(aA, 0) LOADB(bA, 0)
    #pragma unroll
    for (int ks = 0; ks < NK; ks += 2) {
        LOADA(aB, ks + 1) LOADB(bB, ks + 1)
        DOMFMA(aA, bA)
        if (ks + 2 < NK) { LOADA(aA, ks + 2) LOADB(bA, ks + 2) }
        DOMFMA(aB, bB)
    }
    #undef LOADA
    #undef LOADB
    #undef DOMFMA

    if (EPI == 1) {
        __syncthreads();                 // all waves done reading A-slot (aliases u_lds)
        if (tid < BMR) u_lds[tid] = 0.f;
        __syncthreads();
    }

    float upart0 = 0.f, upart1 = 0.f;
    #pragma unroll
    for (int mi = 0; mi < 2; mi++) {
        const int m = mi * 16 + lr;
        #pragma unroll
        for (int nj = 0; nj < NJ; nj++) {
            const int n = wc + nj * 16 + lg * 4;
            f32x4 v = acc[mi][nj];
            if (EPI == 3) {
                *(f32x4*)(sOut + m * 512 + n * 4) = v;
            } else {
                const int po = m * 1024 + ((((n >> 3) ^ (m & 7))) << 4) + (n & 7) * 2;
                if (EPI == 0) {
                    f32x4 bv = *(const f32x4*)(bias + n);
                    Pack4 ps, pc;
                    #pragma unroll
                    for (int r = 0; r < 4; r++) {
                        float s, c;
                        __sincosf(v[r] + bv[r], &s, &c);
                        ps.h[r] = (__bf16)s;
                        pc.h[r] = (__bf16)c;
                    }
                    *(uint2*)(sOut + po) = ps.u2;
                    *(uint2*)((char*)sStash + po) = pc.u2;   // stash is out here
                } else if (EPI == 1) {
                    f32x4 bv = *(const f32x4*)(bias + n);
                    f32x4 wv = *(const f32x4*)(W4 + n);
                    Pack4 pg;
                    #pragma unroll
                    for (int r = 0; r < 4; r++) {
                        float s, c;
                        __sincosf(v[r] + bv[r], &s, &c);
                        if (mi == 0) upart0 += s * wv[r]; else upart1 += s * wv[r];
                        pg.h[r] = (__bf16)(c * wv[r]);
                    }
                    *(uint2*)(sOut + po) = pg.u2;
                } else {  // EPI == 2
                    Pack4 pm = *(const Pack4*)(sStash + po);
                    Pack4 pg;
                    #pragma unroll
                    for (int r = 0; r < 4; r++)
                        pg.h[r] = (__bf16)(v[r] * (float)pm.h[r]);
                    *(uint2*)(sOut + po) = pg.u2;
                }
            }
        }
    }
    if (EPI == 1) {
        upart0 += __shfl_xor(upart0, 16); upart0 += __shfl_xor(upart0, 32);
        upart1 += __shfl_xor(upart1, 16); upart1 += __shfl_xor(upart1, 32);
        if (lg == 0) {
            atomicAdd(&u_lds[lr], upart0);
            atomicAdd(&u_lds[16 + lr], upart1);
        }
    }
}

// ---------- the megakernel ----------
__global__ __launch_bounds__(256, 1) void mega(
    const float* __restrict__ t, const float* __restrict__ W,
    const float* __restrict__ Xi,
    const __bf16* __restrict__ wt0, const __bf16* __restrict__ wt1,
    const __bf16* __restrict__ wt2, const __bf16* __restrict__ wt3,
    const __bf16* __restrict__ wd0, const __bf16* __restrict__ wd1,
    const __bf16* __restrict__ wd2, const __bf16* __restrict__ wd3,
    const float* __restrict__ b0, const float* __restrict__ b1,
    const float* __restrict__ b2, const float* __restrict__ b3,
    const float* __restrict__ W4, const float* __restrict__ b4,
    float* __restrict__ acc) {

    extern __shared__ char lds[];
    char* S0 = lds;
    char* S1 = lds + 32768;
    char* S2 = lds + 65536;
    char* S3 = lds + 98304;
    char* S4 = lds + 131072;
    float* u_lds = (float*)S4;

    const int tid = threadIdx.x;
    const int wgrow = blockIdx.x * BMR;
    const int em = tid >> 3, edg = tid & 7, ed0 = edg * 13;
    const int grow = wgrow + em;

    float x[13];
    #pragma unroll
    for (int i = 0; i < 13; i++) {
        int d = ed0 + i;
        x[i] = (d < DD) ? Xi[d] : 0.f;
    }
    float ytil = 0.f, resid = 0.f, u_reg = 0.f;
    const float b4v = b4[0];

    write_tX(S3, em, edg, ed0, x, t[grow * (NSTEP + 1)]);
    __syncthreads();

    for (int n = 0; n <= NSTEP; n++) {
        // forward
        phase<4, 8, 0>(tid, S3, 256, wt0, K0P, b0, nullptr, S0, S1, nullptr);
        __syncthreads();
        phase<16, 8, 0>(tid, S0, 1024, wt1, HID, b1, nullptr, S2, S3, nullptr);
        __syncthreads();
        phase<16, 8, 0>(tid, S2, 1024, wt2, HID, b2, nullptr, S4, S0, nullptr);
        __syncthreads();
        phase<16, 8, 1>(tid, S4, 1024, wt3, HID, b3, W4, S2, nullptr, u_lds);
        __syncthreads();
        u_reg = u_lds[em] + b4v;
        __syncthreads();
        // backward
        phase<16, 8, 2>(tid, S2, 1024, wd3, HID, nullptr, nullptr, S4, S0, nullptr);
        __syncthreads();
        phase<16, 8, 2>(tid, S4, 1024, wd2, HID, nullptr, nullptr, S2, S3, nullptr);
        __syncthreads();
        phase<16, 8, 2>(tid, S2, 1024, wd1, HID, nullptr, nullptr, S4, S1, nullptr);
        __syncthreads();
        phase<16, 2, 3>(tid, S4, 1024, wd0, HID, nullptr, nullptr, S0, nullptr, nullptr);
        __syncthreads();

        // Euler / terminal (Z f32 in S0)
        const float* Zs = (const float*)(S0 + em * 512);
        if (n < NSTEP) {
            float t0v = t[grow * (NSTEP + 1) + n];
            float t1v = t[grow * (NSTEP + 1) + n + 1];
            const float* Wr0 = W + ((size_t)grow * (NSTEP + 1) + n) * DD;
            const float* Wr1 = Wr0 + DD;
            float pXZ = 0.f, pZs = 0.f;
            #pragma unroll
            for (int i = 0; i < 13; i++) {
                int d = ed0 + i;
                if (d < DD) {
                    float z = Zs[1 + d];
                    float dWv = Wr1[d] - Wr0[d];
                    float s = SIGC * x[i] * dWv;
                    pXZ += x[i] * z;
                    pZs += z * s;
                    x[i] += s;
                }
            }
            pXZ += __shfl_xor(pXZ, 1); pXZ += __shfl_xor(pXZ, 2); pXZ += __shfl_xor(pXZ, 4);
            pZs += __shfl_xor(pZs, 1); pZs += __shfl_xor(pZs, 2); pZs += __shfl_xor(pZs, 4);
            if (edg == 0) {
                if (n >= 1) { float dd = u_reg - ytil; resid += dd * dd; }
                float phi = RC * (u_reg - pXZ);
                ytil = u_reg + phi * (t1v - t0v) + pZs;
            }
            write_tX(S3, em, edg, ed0, x, t1v);
        } else {
            float gX = 0.f, sD = 0.f;
            #pragma unroll
            for (int i = 0; i < 13; i++) {
                int d = ed0 + i;
                if (d < DD) {
                    float z = Zs[1 + d];
                    gX += x[i] * x[i];
                    float e = z - 2.f * x[i];
                    sD += e * e;
                }
            }
            gX += __shfl_xor(gX, 1); gX += __shfl_xor(gX, 2); gX += __shfl_xor(gX, 4);
            sD += __shfl_xor(sD, 1); sD += __shfl_xor(sD, 2); sD += __shfl_xor(sD, 4);
            if (edg == 0) {
                float e = u_reg - gX;
                resid += e * e + sD;
            }
        }
        __syncthreads();
    }

    // block reduction of resid -> one atomic per WG
    float r = resid;
    #pragma unroll
    for (int off = 1; off < 64; off <<= 1) r += __shfl_xor(r, off);
    float* red = (float*)S0;
    if ((tid & 63) == 0) red[tid >> 6] = r;
    __syncthreads();
    if (tid == 0) atomicAdd(acc, red[0] + red[1] + red[2] + red[3]);
}

__global__ void k_final(const float* __restrict__ acc, float* __restrict__ out) {
    out[0] = acc[0] / (float)MM;
}

// ---------- host ----------
extern "C" void kernel_launch(void* const* d_in, const int* in_sizes, int n_in,
                              void* d_out, int out_size, void* d_ws, size_t ws_size,
                              hipStream_t stream) {
    (void)in_sizes; (void)n_in; (void)out_size; (void)ws_size;
    const float* t  = (const float*)d_in[0];
    const float* W  = (const float*)d_in[1];
    const float* Xi = (const float*)d_in[2];
    const float* Wm[5];
    const float* bb[5];
    for (int i = 0; i < 5; i++) {
        Wm[i] = (const float*)d_in[3 + 2 * i];
        bb[i] = (const float*)d_in[4 + 2 * i];
    }

    char* p = (char*)d_ws;
    auto alloc = [&](size_t bytes) -> void* {
        void* r = (void*)p;
        p += (bytes + 255) & ~(size_t)255;
        return r;
    };

    __bf16* wt[4];
    wt[0] = (__bf16*)alloc((size_t)HID * K0P * 2);
    for (int i = 1; i < 4; i++) wt[i] = (__bf16*)alloc((size_t)HID * HID * 2);
    __bf16* wd[4];
    wd[0] = (__bf16*)alloc((size_t)K0P * HID * 2);
    for (int i = 1; i < 4; i++) wd[i] = (__bf16*)alloc((size_t)HID * HID * 2);
    float* acc = (float*)alloc(256);

    hipMemsetAsync(acc, 0, 256, stream);

    k_transpose<<<(HID * K0P + 255) / 256, 256, 0, stream>>>(Wm[0], wt[0], 101, K0P, HID);
    for (int i = 1; i < 4; i++)
        k_transpose<<<(HID * HID + 255) / 256, 256, 0, stream>>>(Wm[i], wt[i], HID, HID, HID);
    k_cast<<<(K0P * HID + 255) / 256, 256, 0, stream>>>(Wm[0], wd[0], 101, K0P, HID);
    for (int i = 1; i < 4; i++)
        k_cast<<<(HID * HID + 255) / 256, 256, 0, stream>>>(Wm[i], wd[i], HID, HID, HID);

    static bool attrSet = false;
    if (!attrSet) {
        hipFuncSetAttribute((const void*)mega,
                            hipFuncAttributeMaxDynamicSharedMemorySize, 163840);
        attrSet = true;
    }

    mega<<<dim3(NWG), dim3(256), 163840, stream>>>(
        t, W, Xi,
        wt[0], wt[1], wt[2], wt[3],
        wd[0], wd[1], wd[2], wd[3],
        bb[0], bb[1], bb[2], bb[3],
        Wm[4], bb[4], acc);

    k_final<<<1, 1, 0, stream>>>(acc, (float*)d_out);
}